// Round 12
// baseline (737.238 us; speedup 1.0000x reference)
//
#include <hip/hip_runtime.h>
#include <hip/hip_cooperative_groups.h>

namespace cg = cooperative_groups;

#define NODE_DIM 8

typedef __attribute__((ext_vector_type(8))) short short8;
typedef __attribute__((ext_vector_type(4))) float f32x4;

// 8-term dot; param must not be named w/x/y/z (macro hits member access).
#define DOT8(xv, WT) ((xv)[0]*(WT)[0] + (xv)[1]*(WT)[1] + (xv)[2]*(WT)[2] + (xv)[3]*(WT)[3] + \
                      (xv)[4]*(WT)[4] + (xv)[5]*(WT)[5] + (xv)[6]*(WT)[6] + (xv)[7]*(WT)[7])

// fp32 pair -> packed bf16 via round-half-up + byte-perm (3 VALU).
static __device__ __forceinline__ unsigned pk2_bf16(float a, float b) {
    const unsigned ua = __float_as_uint(a) + 0x8000u;
    const unsigned ub = __float_as_uint(b) + 0x8000u;
    return __builtin_amdgcn_perm(ub, ua, 0x07060302u);
}

static __device__ __forceinline__ short bf16_rne(float v) {
    unsigned u = __float_as_uint(v);
    u = (u + 0x7fffu + ((u >> 16) & 1u)) >> 16;
    return (short)u;
}

// ===========================================================================
// ONE cooperative kernel: zero -> hist(+rank) -> scan(3 lvl) -> dstA expand
// -> record scatter (atomic-free) -> MFMA edge + LDS segment reduce ->
// node transform/pool -> MLP head.  8 grid.sync()s replace 9 dispatches
// (R11: ~236us lived in small middle kernels + launch gaps).
// ===========================================================================
__global__ __launch_bounds__(256)
void mega_kernel(const float* __restrict__ x,
                 const float* __restrict__ ea,
                 const int* __restrict__ eidx,
                 const int* __restrict__ batch,
                 const float* __restrict__ ratios,
                 const int* __restrict__ ids,
                 const float* __restrict__ emb,
                 const float* __restrict__ W1, const float* __restrict__ b1,
                 const float* __restrict__ W2, const float* __restrict__ b2,
                 const float* __restrict__ root, const float* __restrict__ conv_bias,
                 const float* __restrict__ fc0w, const float* __restrict__ fc0b,
                 const float* __restrict__ fc1w, const float* __restrict__ fc1b,
                 const float* __restrict__ fc2w, const float* __restrict__ fc2b,
                 float* __restrict__ out,
                 int4* __restrict__ rec, int* __restrict__ dstA,
                 int* __restrict__ rank, int* __restrict__ rowptr,
                 float* __restrict__ s, int* __restrict__ cnt,
                 float* __restrict__ gsum, int* __restrict__ bsum,
                 int* __restrict__ boff,
                 int N, int E, int G)
{
    cg::grid_group grid = cg::this_grid();

    __shared__ __align__(16) short lds_b[18 * 64 * 8];   // B fragments (18 KB)
    __shared__ float lds_c[64 * 33];                     // C tile / scan / red / mlp scratch
    __shared__ int   lds_d[64];

    const int t        = threadIdx.x;
    const int bid      = blockIdx.x;
    const int nthreads = (int)(gridDim.x * blockDim.x);
    const int gtid     = bid * 256 + t;
    const int NB       = (N + 255) >> 8;

    // ---- stage B fragments (bf16 RNE, frag-order); consumed in edge phase ----
    for (int f = t; f < 18 * 64 * 8; f += 256) {
        const int j   = f & 7;
        const int ln  = (f >> 3) & 63;
        const int fid = f >> 9;
        const int kk  = fid >> 1, ot = fid & 1;
        const int qq  = ln >> 4, ol = ln & 15;
        float v;
        if (kk < 8) v = W2[(kk * 4 + qq) * 256 + j * 32 + ot * 16 + ol];
        else        v = (qq == 0) ? b2[j * 32 + ot * 16 + ol] : 0.f;
        lds_b[f] = bf16_rne(v);
    }

    // ---- phase 0: zero s / cnt / gsum ----
    for (int i = gtid; i < N * 32; i += nthreads) s[i] = 0.f;
    for (int i = gtid; i < N;      i += nthreads) cnt[i] = 0;
    for (int i = gtid; i < G * 32; i += nthreads) gsum[i] = 0.f;
    grid.sync();

    // ---- phase 1: histogram + per-edge rank (atomic return value) ----
    for (int e = gtid; e < E; e += nthreads)
        rank[e] = atomicAdd(&cnt[eidx[E + e]], 1);
    grid.sync();

    // ---- phase 2: block-local scan (blocks 0..NB-1) ----
    int* shi = (int*)lds_c;
    if (bid < NB) {
        const int i = bid * 256 + t;
        const int v = (i < N) ? cnt[i] : 0;
        shi[t] = v;
        __syncthreads();
#pragma unroll
        for (int off = 1; off < 256; off <<= 1) {
            int add = 0;
            if (t >= off) add = shi[t - off];
            __syncthreads();
            if (t >= off) shi[t] += add;
            __syncthreads();
        }
        if (i < N) rowptr[i] = shi[t] - v;
        if (t == 255) bsum[bid] = shi[255];
    }
    grid.sync();

    // ---- phase 3: scan of block sums (block 0) ----
    if (bid == 0) {
        const int v = (t < NB) ? bsum[t] : 0;
        shi[t] = v;
        __syncthreads();
#pragma unroll
        for (int off = 1; off < 256; off <<= 1) {
            int add = 0;
            if (t >= off) add = shi[t - off];
            __syncthreads();
            if (t >= off) shi[t] += add;
            __syncthreads();
        }
        if (t < NB) boff[t] = shi[t] - v;
    }
    grid.sync();

    // ---- phase 4: finalize rowptr + expand dstA (sequential writes) ----
    for (int i = gtid; i < N; i += nthreads) {
        const int r = rowptr[i] + boff[i >> 8];
        rowptr[i] = r;
        const int c = cnt[i];
        for (int p2 = 0; p2 < c; ++p2) dstA[r + p2] = i;
    }
    grid.sync();

    // ---- phase 5: scatter 16B edge records into sorted order (no atomics) ----
    for (int e = gtid; e < E; e += nthreads) {
        const int d   = eidx[E + e];
        const int pos = rowptr[d] + rank[e];
        int4 r;
        r.x = eidx[e];
        r.y = __float_as_int(ea[3 * e]);
        r.z = __float_as_int(ea[3 * e + 1]);
        r.w = __float_as_int(ea[3 * e + 2]);
        rec[pos] = r;
    }
    grid.sync();

    // ---- phase 6: MFMA edge compute + in-LDS segment reduce ----
    {
        const int lane = t & 63;
        const int e_l  = lane & 15;
        const int q    = lane >> 4;
        const int wv   = t >> 6;

        float w10[8], w11[8], w12[8], b1r[8];
#pragma unroll
        for (int t2 = 0; t2 < 8; ++t2) {
            const int k = 4 * t2 + q;
            w10[t2] = W1[k]; w11[t2] = W1[32 + k]; w12[t2] = W1[64 + k]; b1r[t2] = b1[k];
        }

        const int ntile = (E + 63) >> 6;
        for (int tile = bid; tile < ntile; tile += (int)gridDim.x) {
            const int tbase = tile << 6;

            int dval = 0;
            if (t < 64) dval = (tbase + t < E) ? dstA[tbase + t] : -1;

            int slot = tbase + wv * 16 + e_l; if (slot >= E) slot = E - 1;
            const int4  rcd = rec[slot];
            const float ea0 = __int_as_float(rcd.y);
            const float ea1 = __int_as_float(rcd.z);
            const float ea2 = __int_as_float(rcd.w);
            const float4 xa = *(const float4*)(x + (size_t)(unsigned)rcd.x * 8);
            const float4 xb = *(const float4*)(x + (size_t)(unsigned)rcd.x * 8 + 4);
            const float xr[8] = {xa.x, xa.y, xa.z, xa.w, xb.x, xb.y, xb.z, xb.w};

            float h[8];
#pragma unroll
            for (int t2 = 0; t2 < 8; ++t2) {
                const float z = b1r[t2] + ea0 * w10[t2] + ea1 * w11[t2] + ea2 * w12[t2];
                h[t2] = z > 0.f ? z : 0.f;
            }

            f32x4 acc0 = {0.f, 0.f, 0.f, 0.f};
            f32x4 acc1 = {0.f, 0.f, 0.f, 0.f};
#pragma unroll
            for (int kk = 0; kk < 9; ++kk) {
                const float hk = (kk < 8) ? h[kk] : 1.f;
                union { short8 v; unsigned u[4]; } af;
#pragma unroll
                for (int p2 = 0; p2 < 4; ++p2)
                    af.u[p2] = pk2_bf16(hk * xr[2 * p2], hk * xr[2 * p2 + 1]);
                const short8 bf0 = *(const short8*)&lds_b[((kk * 2 + 0) * 64 + lane) * 8];
                const short8 bf1 = *(const short8*)&lds_b[((kk * 2 + 1) * 64 + lane) * 8];
                acc0 = __builtin_amdgcn_mfma_f32_16x16x32_bf16(af.v, bf0, acc0, 0, 0, 0);
                acc1 = __builtin_amdgcn_mfma_f32_16x16x32_bf16(af.v, bf1, acc1, 0, 0, 0);
            }

            __syncthreads();   // lds_c free (prev reduce / scan scratch done)
#pragma unroll
            for (int r = 0; r < 4; ++r) {
                const int row = wv * 16 + q * 4 + r;
                lds_c[row * 33 + e_l]      = acc0[r];
                lds_c[row * 33 + 16 + e_l] = acc1[r];
            }
            if (t < 64) lds_d[t] = dval;
            __syncthreads();

            // segment reduce: 32 cols x 8 chunks of 8 rows (dst sorted)
            {
                const int o   = t & 31;
                const int rlo = (t >> 5) * 8;
                int   cur = -1;
                float run = 0.f;
#pragma unroll
                for (int r2 = rlo; r2 < rlo + 8; ++r2) {
                    const int d = lds_d[r2];
                    const float v = lds_c[r2 * 33 + o];
                    if (d != cur) {
                        if (cur >= 0) atomicAdd(&s[(size_t)cur * 32 + o], run);
                        cur = d; run = v;
                    } else {
                        run += v;
                    }
                }
                if (cur >= 0) atomicAdd(&s[(size_t)cur * 32 + o], run);
            }
        }
    }
    grid.sync();

    // ---- phase 7: node transform + pool ----
    {
        const int o    = t & 31;
        const int slot = t >> 5;
        float rootr[8];
#pragma unroll
        for (int i = 0; i < 8; ++i) rootr[i] = root[i * 32 + o];
        const float cb = conv_bias[o];

        const int nchunk = (N + 7) >> 3;
        for (int ch = bid; ch < nchunk; ch += (int)gridDim.x) {
            const int base = ch * 8;
            const int n    = base + slot;

            float v = 0.f;
            int   b = 0;
            if (n < N) {
                b = batch[n];
                const int   c    = cnt[n];
                const float rinv = 1.f / (float)(c > 1 ? c : 1);
                const float* xp  = x + (size_t)n * 8;
                float xv[8];
#pragma unroll
                for (int i = 0; i < 8; ++i) xv[i] = xp[i];
                const float t2 = s[(size_t)n * 32 + o] * rinv + cb + DOT8(xv, rootr);
                v = t2 > 0.f ? t2 : 0.f;
            }

            const int nlast  = (base + 7 < N) ? base + 7 : N - 1;
            const int bfirst = batch[base];
            const int blast  = batch[nlast];

            __syncthreads();          // lds_c reusable
            lds_c[t] = v;
            __syncthreads();
            if (bfirst == blast && base + 7 < N) {
                if (t < 32) {
                    float p2 = 0.f;
#pragma unroll
                    for (int c2 = 0; c2 < 8; ++c2) p2 += lds_c[t + 32 * c2];
                    atomicAdd(&gsum[bfirst * 32 + t], p2);
                }
            } else {
                if (n < N) atomicAdd(&gsum[b * 32 + o], v);
            }
        }
    }
    grid.sync();

    // ---- phase 8: MLP head (blocks 0..G-1) ----
    if (bid < G) {
        float* zs = lds_c;            // [96]
        float* z1 = lds_c + 96;       // [64]
        float* z2 = lds_c + 160;      // [32]
        int*   seg = (int*)(lds_c + 192);

        const int g = bid;
        if (t < 2) {
            const int target = g + t;
            int lo = 0, hi = N;
            while (lo < hi) {
                const int mid = (lo + hi) >> 1;
                if (batch[mid] < target) lo = mid + 1; else hi = mid;
            }
            seg[t] = lo;
        }
        __syncthreads();

        float c = (float)(seg[1] - seg[0]);
        if (c < 1.f) c = 1.f;

        if (t < 32) zs[t] = gsum[g * 32 + t] / c;
        if (t >= 32 && t < 96) {
            const int j = t - 32;
            float u = 0.f;
#pragma unroll
            for (int r = 0; r < 5; ++r) u += ratios[r] * emb[(size_t)ids[r] * 64 + j];
            zs[32 + j] = u;
        }
        __syncthreads();

        if (t < 64) {
            float a = fc0b[t];
            for (int k = 0; k < 96; ++k) a += zs[k] * fc0w[k * 64 + t];
            z1[t] = a > 0.f ? a : 0.f;
        }
        __syncthreads();

        if (t < 32) {
            float a = fc1b[t];
            for (int k = 0; k < 64; ++k) a += z1[k] * fc1w[k * 32 + t];
            z2[t] = a > 0.f ? a : 0.f;
        }
        __syncthreads();

        if (t == 0) {
            float a = fc2b[0];
            for (int k = 0; k < 32; ++k) a += z2[k] * fc2w[k];
            out[g] = a;
        }
    }
}

// ---------------------------------------------------------------------------
extern "C" void kernel_launch(void* const* d_in, const int* in_sizes, int n_in,
                              void* d_out, int out_size, void* d_ws, size_t ws_size,
                              hipStream_t stream)
{
    const float* x         = (const float*)d_in[0];
    const float* ea        = (const float*)d_in[1];
    const float* ratios    = (const float*)d_in[2];
    const int*   eidx      = (const int*)  d_in[3];
    const int*   batch     = (const int*)  d_in[4];
    const int*   ids       = (const int*)  d_in[5];
    const float* W1        = (const float*)d_in[6];
    const float* b1        = (const float*)d_in[7];
    const float* W2        = (const float*)d_in[8];
    const float* b2        = (const float*)d_in[9];
    const float* emb       = (const float*)d_in[10];
    const float* root      = (const float*)d_in[11];
    const float* conv_bias = (const float*)d_in[12];
    const float* fc0w      = (const float*)d_in[13];
    const float* fc0b      = (const float*)d_in[14];
    const float* fc1w      = (const float*)d_in[15];
    const float* fc1b      = (const float*)d_in[16];
    const float* fc2w      = (const float*)d_in[17];
    const float* fc2b      = (const float*)d_in[18];

    int N = in_sizes[0] / NODE_DIM;   // 50000
    int E = in_sizes[1] / 3;          // 1000000
    int G = out_size;                 // 128

    char* p = (char*)d_ws;
    int4*  rec    = (int4*)p;   p += (size_t)E * 16;
    int*   dstA   = (int*)p;    p += (size_t)E * 4;
    int*   rank   = (int*)p;    p += (size_t)E * 4;
    int*   rowptr = (int*)p;    p += (size_t)(N + 1) * 4;
    float* s      = (float*)p;  p += (size_t)N * 32 * 4;
    int*   cnt    = (int*)p;    p += (size_t)N * 4;
    float* gsum   = (float*)p;  p += (size_t)G * 32 * 4;
    int*   bsum   = (int*)p;    p += 256 * 4;
    int*   boff   = (int*)p;    p += 256 * 4;

    float* out = (float*)d_out;

    // Co-resident grid: LDS 27.1KB/block -> ~5-6 blocks/CU on 256 CUs.
    int maxB = 0;
    (void)hipOccupancyMaxActiveBlocksPerMultiprocessor(&maxB, mega_kernel, 256, 0);
    int grid = maxB * 256;
    if (grid > 1536) grid = 1536;
    if (grid < 256)  grid = 256;   // floor covers NB=196 and G=128 phases

    void* args[] = {
        (void*)&x, (void*)&ea, (void*)&eidx, (void*)&batch, (void*)&ratios,
        (void*)&ids, (void*)&emb, (void*)&W1, (void*)&b1, (void*)&W2, (void*)&b2,
        (void*)&root, (void*)&conv_bias, (void*)&fc0w, (void*)&fc0b,
        (void*)&fc1w, (void*)&fc1b, (void*)&fc2w, (void*)&fc2b, (void*)&out,
        (void*)&rec, (void*)&dstA, (void*)&rank, (void*)&rowptr, (void*)&s,
        (void*)&cnt, (void*)&gsum, (void*)&bsum, (void*)&boff,
        (void*)&N, (void*)&E, (void*)&G
    };
    (void)hipLaunchCooperativeKernel((const void*)mega_kernel, dim3(grid), dim3(256),
                                     args, 0, stream);
}